// Round 2
// baseline (348.437 us; speedup 1.0000x reference)
//
#include <hip/hip_runtime.h>
#include <stdint.h>

#define NROW   8192
#define CDIM   256
#define NCODE  16384
#define MARGIN 1.5e-4f

typedef short short8 __attribute__((ext_vector_type(8)));
typedef float floatx4 __attribute__((ext_vector_type(4)));

__device__ inline ushort f2bf(float f) {
    unsigned u = __builtin_bit_cast(unsigned, f);
    unsigned r = (u + 0x7fffu + ((u >> 16) & 1u)) >> 16;
    return (ushort)r;
}
__device__ inline unsigned fsort(float v) {
    unsigned u = __builtin_bit_cast(unsigned, v);
    return (u >> 31) ? ~u : (u | 0x80000000u);
}
__device__ inline float funsort(unsigned s) {
    unsigned u = (s & 0x80000000u) ? (s & 0x7fffffffu) : ~s;
    return __builtin_bit_cast(float, u);
}

// ---------------------------------------------------------------------------
// x (B,C,H,W) fp32 -> xf32[n][c] and xbf[n][c] (bf16), n = b*1024 + hw
// ---------------------------------------------------------------------------
__global__ __launch_bounds__(256) void prep_x(const float* __restrict__ x,
                                              float* __restrict__ xf32,
                                              ushort* __restrict__ xbf) {
    __shared__ float tile[32][33];
    const int b = blockIdx.x, ht = blockIdx.y, ct = blockIdx.z;
    const int t = threadIdx.x;
    const int hw0 = ht * 32, c0 = ct * 32;
    {
        const int cc = t >> 5, hh = t & 31;
        #pragma unroll
        for (int i = 0; i < 4; ++i) {
            int cl = cc + i * 8;
            tile[cl][hh] = x[((size_t)(b * 256 + c0 + cl) << 10) + hw0 + hh];
        }
    }
    __syncthreads();
    {
        const int col = t & 31, row = t >> 5;
        #pragma unroll
        for (int i = 0; i < 4; ++i) {
            int r = row + i * 8;
            float v = tile[col][r];
            size_t o = ((size_t)(b * 1024 + hw0 + r) << 8) + c0 + col;
            xf32[o] = v;
            xbf[o] = f2bf(v);
        }
    }
}

// ---------------------------------------------------------------------------
// S1[n] = numpy-pairwise fp32 sum of fl(x_k^2) over the row (exact np mirror)
// ---------------------------------------------------------------------------
__global__ __launch_bounds__(256) void s1k(const float* __restrict__ xf32,
                                           float* __restrict__ S1a) {
#pragma clang fp contract(off)
    const int n = blockIdx.x * 256 + threadIdx.x;
    const float* a0 = xf32 + ((size_t)n << 8);
    float hs[2];
    #pragma unroll
    for (int h = 0; h < 2; ++h) {
        const float* a = a0 + h * 128;
        float r[8];
        #pragma unroll
        for (int l = 0; l < 8; ++l) { float v = a[l]; r[l] = v * v; }
        for (int i = 8; i < 128; i += 8) {
            #pragma unroll
            for (int l = 0; l < 8; ++l) { float v = a[i + l]; r[l] = r[l] + v * v; }
        }
        hs[h] = ((r[0] + r[1]) + (r[2] + r[3])) + ((r[4] + r[5]) + (r[6] + r[7]));
    }
    S1a[n] = hs[0] + hs[1];
}

// ---------------------------------------------------------------------------
// per code j: bf16 copy + S2[j] via exact numpy pairwise mirror
// ---------------------------------------------------------------------------
__global__ __launch_bounds__(256) void prep_w2(const float* __restrict__ w,
                                               ushort* __restrict__ wbf,
                                               float* __restrict__ S2a) {
#pragma clang fp contract(off)
    const int j = blockIdx.x * 256 + threadIdx.x;
    const float* row = w + ((size_t)j << 8);
    ushort* orow = wbf + ((size_t)j << 8);
    float hs[2];
    #pragma unroll
    for (int h = 0; h < 2; ++h) {
        const float* a = row + h * 128;
        float r[8];
        #pragma unroll
        for (int l = 0; l < 8; ++l) { float v = a[l]; r[l] = v * v; }
        for (int i = 8; i < 128; i += 8) {
            #pragma unroll
            for (int l = 0; l < 8; ++l) { float v = a[i + l]; r[l] = r[l] + v * v; }
        }
        hs[h] = ((r[0] + r[1]) + (r[2] + r[3])) + ((r[4] + r[5]) + (r[6] + r[7]));
    }
    S2a[j] = hs[0] + hs[1];
    for (int i = 0; i < 256; i += 8) {
        ushort u8[8];
        #pragma unroll
        for (int l = 0; l < 8; ++l) u8[l] = f2bf(row[i + l]);
        *(ushort4*)(orow + i)     = make_ushort4(u8[0], u8[1], u8[2], u8[3]);
        *(ushort4*)(orow + i + 4) = make_ushort4(u8[4], u8[5], u8[6], u8[7]);
    }
}

// ---------------------------------------------------------------------------
// bf16 MFMA GEMM; per (row, 128-col block) emit top-2 (approx score, index)
// packed as u64 keys: (sortable_fp32 << 32) | j
// ---------------------------------------------------------------------------
__global__ __launch_bounds__(256) void gemm_min(const ushort* __restrict__ A,
                                                const ushort* __restrict__ Bm,
                                                const float* __restrict__ cnorm,
                                                ulonglong2* __restrict__ bm2) {
    __shared__ __attribute__((aligned(16))) ushort As[128][72];
    __shared__ __attribute__((aligned(16))) ushort Bs[128][72];
    __shared__ unsigned long long sm2[2][128][2];

    const int n0 = blockIdx.x * 128;
    const int j0 = blockIdx.y * 128;
    const int t  = threadIdx.x;
    const int wv = t >> 6, l = t & 63;
    const int wr = wv >> 1, wc = wv & 1;
    const int q  = l >> 4, c = l & 15;

    floatx4 acc[4][4];
    #pragma unroll
    for (int mi = 0; mi < 4; ++mi)
        #pragma unroll
        for (int ni = 0; ni < 4; ++ni)
            acc[mi][ni] = (floatx4){0.f, 0.f, 0.f, 0.f};

    const int trow = t >> 3;
    const int tcol = (t & 7) * 8;

    for (int kb = 0; kb < 4; ++kb) {
        if (kb) __syncthreads();
        #pragma unroll
        for (int p = 0; p < 4; ++p) {
            int row = p * 32 + trow;
            *(uint4*)&As[row][tcol] =
                *(const uint4*)&A[((size_t)(n0 + row) << 8) + kb * 64 + tcol];
            *(uint4*)&Bs[row][tcol] =
                *(const uint4*)&Bm[((size_t)(j0 + row) << 8) + kb * 64 + tcol];
        }
        __syncthreads();
        #pragma unroll
        for (int kk = 0; kk < 2; ++kk) {
            short8 af[4], bf[4];
            #pragma unroll
            for (int mi = 0; mi < 4; ++mi)
                af[mi] = *(const short8*)&As[wr * 64 + mi * 16 + c][kk * 32 + q * 8];
            #pragma unroll
            for (int ni = 0; ni < 4; ++ni)
                bf[ni] = *(const short8*)&Bs[wc * 64 + ni * 16 + c][kk * 32 + q * 8];
            #pragma unroll
            for (int mi = 0; mi < 4; ++mi)
                #pragma unroll
                for (int ni = 0; ni < 4; ++ni)
                    acc[mi][ni] = __builtin_amdgcn_mfma_f32_16x16x32_bf16(
                        af[mi], bf[ni], acc[mi][ni], 0, 0, 0);
        }
    }

    float cn[4];
    #pragma unroll
    for (int ni = 0; ni < 4; ++ni) cn[ni] = cnorm[j0 + wc * 64 + ni * 16 + c];

    #pragma unroll
    for (int mi = 0; mi < 4; ++mi) {
        #pragma unroll
        for (int r = 0; r < 4; ++r) {
            unsigned long long k1 = ~0ull, k2 = ~0ull;
            #pragma unroll
            for (int ni = 0; ni < 4; ++ni) {
                float v = fmaf(-2.f, acc[mi][ni][r], cn[ni]);
                unsigned long long key = ((unsigned long long)fsort(v) << 32)
                                       | (unsigned)(j0 + wc * 64 + ni * 16 + c);
                if (key < k1) { k2 = k1; k1 = key; }
                else if (key < k2) { k2 = key; }
            }
            #pragma unroll
            for (int off = 1; off <= 8; off <<= 1) {
                unsigned long long o1 = __shfl_xor(k1, off);
                unsigned long long o2 = __shfl_xor(k2, off);
                unsigned long long n1 = k1 < o1 ? k1 : o1;
                unsigned long long mx = k1 < o1 ? o1 : k1;
                unsigned long long n2 = k2 < o2 ? k2 : o2;
                k1 = n1;
                k2 = mx < n2 ? mx : n2;
            }
            if (c == 0) {
                int rr = wr * 64 + mi * 16 + q * 4 + r;
                sm2[wc][rr][0] = k1;
                sm2[wc][rr][1] = k2;
            }
        }
    }
    __syncthreads();
    if (t < 128) {
        unsigned long long a1 = sm2[0][t][0], a2 = sm2[0][t][1];
        unsigned long long b1 = sm2[1][t][0], b2 = sm2[1][t][1];
        unsigned long long n1 = a1 < b1 ? a1 : b1;
        unsigned long long mx = a1 < b1 ? b1 : a1;
        unsigned long long n2 = a2 < b2 ? a2 : b2;
        unsigned long long k2 = mx < n2 ? mx : n2;
        bm2[((size_t)(n0 + t) << 7) + blockIdx.y] = make_ulonglong2(n1, k2);
    }
}

// ---------------------------------------------------------------------------
// Exact np-fp32 rescore of pruned candidates; argmin w/ first-index ties.
// ---------------------------------------------------------------------------
__global__ __launch_bounds__(256) void rescore2(const ulonglong2* __restrict__ bm2,
                                                const float* __restrict__ xf32,
                                                const float* __restrict__ w,
                                                const float* __restrict__ S1a,
                                                const float* __restrict__ S2a,
                                                int* __restrict__ idxb,
                                                float* __restrict__ xcode) {
    __shared__ float xrow[256];
    __shared__ unsigned long long redk[256];
    __shared__ int cj[128];
    __shared__ int fb[128];
    __shared__ int nc, nf;
    const int n = blockIdx.x, t = threadIdx.x;
    xrow[t] = xf32[((size_t)n << 8) + t];
    if (t == 0) { nc = 0; nf = 0; }
    unsigned long long k1 = ~0ull;
    float v1 = 0.f, v2 = 0.f; int j1 = 0;
    if (t < 128) {
        ulonglong2 e = bm2[((size_t)n << 7) + t];
        k1 = e.x;
        v1 = funsort((unsigned)(e.x >> 32));
        v2 = funsort((unsigned)(e.y >> 32));
        j1 = (int)(e.x & 0xffffffffu);
    }
    redk[t] = k1;
    __syncthreads();
    for (int s = 128; s > 0; s >>= 1) {
        if (t < s) { if (redk[t + s] < redk[t]) redk[t] = redk[t + s]; }
        __syncthreads();
    }
    const float thr = funsort((unsigned)(redk[0] >> 32)) + MARGIN;
    if (t < 128 && v1 <= thr) {
        if (v2 <= thr) { int p = atomicAdd(&nf, 1); fb[p] = t; }
        else           { int p = atomicAdd(&nc, 1); cj[p] = j1; }
    }
    __syncthreads();
    const int total = nc + nf * 128;
    const float S1n = S1a[n];
    unsigned long long best = ~0ull;
    for (int it = t; it < total; it += 256) {
        int j;
        if (it < nc) j = cj[it];
        else { int q2 = it - nc; j = fb[q2 >> 7] * 128 + (q2 & 127); }
        const float* wr = w + ((size_t)j << 8);
        float g = 0.f;
        for (int k = 0; k < 256; ++k) g = fmaf(xrow[k], wr[k], g);  // sequential FMA = BLAS k-order
        float d = (S1n + S2a[j]) - 2.0f * g;                        // fl32(fl32(S1+S2) - 2G)
        unsigned long long key = ((unsigned long long)fsort(d) << 32) | (unsigned)j;
        if (key < best) best = key;
    }
    __syncthreads();
    redk[t] = best;
    __syncthreads();
    for (int s = 128; s > 0; s >>= 1) {
        if (t < s) { if (redk[t + s] < redk[t]) redk[t] = redk[t + s]; }
        __syncthreads();
    }
    if (t == 0) {
        int J = (int)(redk[0] & 0xffffffffu);
        idxb[n] = J;
        xcode[n] = (float)J;
    }
}

// ---------------------------------------------------------------------------
// xq_img gather + loss
// ---------------------------------------------------------------------------
__global__ __launch_bounds__(256) void outputs_k(const float* __restrict__ x,
                                                 const float* __restrict__ w,
                                                 const int* __restrict__ idxb,
                                                 float* __restrict__ out,
                                                 float* __restrict__ loss) {
    const int b = blockIdx.x, hq = blockIdx.y, cs = blockIdx.z;
    const int t = threadIdx.x;
    const int hw = hq * 256 + t;
    const int n = (b << 10) + hw;
    const int id = idxb[n];
    float lacc = 0.f;
    for (int ci = 0; ci < 32; ++ci) {
        const int c_ = cs * 32 + ci;
        const size_t oo = ((size_t)((b << 8) + c_) << 10) + hw;
        float wv = w[((size_t)id << 8) + c_];
        float xv = x[oo];
        out[oo] = wv;
        float d = wv - xv;
        lacc = fmaf(d, d, lacc);
    }
    #pragma unroll
    for (int off = 32; off; off >>= 1) lacc += __shfl_xor(lacc, off);
    __shared__ float part[4];
    if ((t & 63) == 0) part[t >> 6] = lacc;
    __syncthreads();
    if (t == 0) {
        float p = part[0] + part[1] + part[2] + part[3];
        atomicAdd(loss, p * (1.25f / 2097152.0f));
    }
}

// ---------------------------------------------------------------------------
extern "C" void kernel_launch(void* const* d_in, const int* in_sizes, int n_in,
                              void* d_out, int out_size, void* d_ws, size_t ws_size,
                              hipStream_t stream) {
    const float* x = (const float*)d_in[0];
    const float* w = (const float*)d_in[1];
    float* out = (float*)d_out;

    char* ws = (char*)d_ws;
    const size_t MB = 1024u * 1024u;
    ushort*     xbf   = (ushort*)(ws);                  //  4 MiB
    float*      xf32  = (float*) (ws + 4 * MB);         //  8 MiB
    ushort*     wbf   = (ushort*)(ws + 12 * MB);        //  8 MiB
    float*      S2a   = (float*) (ws + 20 * MB);        // 64 KiB
    float*      S1a   = (float*) (ws + 20 * MB + 65536);// 32 KiB
    ulonglong2* bm2   = (ulonglong2*)(ws + 21 * MB);    // 16 MiB
    int*        idxb  = (int*)   (ws + 37 * MB);        // 32 KiB

    float* loss_ptr  = out + 2097152;
    float* xcode_ptr = out + 2097153;

    hipMemsetAsync((void*)loss_ptr, 0, 4, stream);

    prep_x  <<<dim3(8, 32, 8), 256, 0, stream>>>(x, xf32, xbf);
    prep_w2 <<<dim3(64),       256, 0, stream>>>(w, wbf, S2a);
    s1k     <<<dim3(32),       256, 0, stream>>>(xf32, S1a);
    gemm_min<<<dim3(64, 128),  256, 0, stream>>>(xbf, wbf, S2a, bm2);
    rescore2<<<dim3(8192),     256, 0, stream>>>(bm2, xf32, w, S1a, S2a, idxb, xcode_ptr);
    outputs_k<<<dim3(8, 4, 8), 256, 0, stream>>>(x, w, idxb, out, loss_ptr);
}

// Round 3
// 316.325 us; speedup vs baseline: 1.1015x; 1.1015x over previous
//
#include <hip/hip_runtime.h>
#include <stdint.h>

#define NROW   8192
#define CDIM   256
#define NCODE  16384
#define MARGIN 1.5e-4f

typedef short short8 __attribute__((ext_vector_type(8)));
typedef float floatx4 __attribute__((ext_vector_type(4)));

__device__ inline ushort f2bf(float f) {
    unsigned u = __builtin_bit_cast(unsigned, f);
    unsigned r = (u + 0x7fffu + ((u >> 16) & 1u)) >> 16;
    return (ushort)r;
}
__device__ inline unsigned fsort(float v) {
    unsigned u = __builtin_bit_cast(unsigned, v);
    return (u >> 31) ? ~u : (u | 0x80000000u);
}

__device__ inline void gl_lds16(const ushort* g, ushort* lds) {
    __builtin_amdgcn_global_load_lds(
        (const __attribute__((address_space(1))) unsigned int*)(g),
        (__attribute__((address_space(3))) unsigned int*)(lds),
        16, 0, 0);
}

// ---------------------------------------------------------------------------
// x (B,C,H,W) fp32 -> xf32[n][c] and xbf[n][c] (bf16), n = b*1024 + hw
// ---------------------------------------------------------------------------
__global__ __launch_bounds__(256) void prep_x(const float* __restrict__ x,
                                              float* __restrict__ xf32,
                                              ushort* __restrict__ xbf) {
    __shared__ float tile[32][33];
    const int b = blockIdx.x, ht = blockIdx.y, ct = blockIdx.z;
    const int t = threadIdx.x;
    const int hw0 = ht * 32, c0 = ct * 32;
    {
        const int cc = t >> 5, hh = t & 31;
        #pragma unroll
        for (int i = 0; i < 4; ++i) {
            int cl = cc + i * 8;
            tile[cl][hh] = x[((size_t)(b * 256 + c0 + cl) << 10) + hw0 + hh];
        }
    }
    __syncthreads();
    {
        const int col = t & 31, row = t >> 5;
        #pragma unroll
        for (int i = 0; i < 4; ++i) {
            int r = row + i * 8;
            float v = tile[col][r];
            size_t o = ((size_t)(b * 1024 + hw0 + r) << 8) + c0 + col;
            xf32[o] = v;
            xbf[o] = f2bf(v);
        }
    }
}

// ---------------------------------------------------------------------------
// 2 threads per code j (one per 128-half): bf16 copy + exact np pairwise S2
// ---------------------------------------------------------------------------
__global__ __launch_bounds__(256) void prep_w2(const float* __restrict__ w,
                                               ushort* __restrict__ wbf,
                                               float* __restrict__ S2a) {
#pragma clang fp contract(off)
    const int gt = blockIdx.x * 256 + threadIdx.x;
    const int j = gt >> 1, h = gt & 1;
    const float* a = w + ((size_t)j << 8) + h * 128;
    ushort* orow = wbf + ((size_t)j << 8) + h * 128;
    float r8[8];
    #pragma unroll
    for (int l = 0; l < 8; ++l) { float v = a[l]; r8[l] = v * v; }
    for (int i = 8; i < 128; i += 8) {
        #pragma unroll
        for (int l = 0; l < 8; ++l) { float v = a[i + l]; r8[l] = r8[l] + v * v; }
    }
    float hs = ((r8[0] + r8[1]) + (r8[2] + r8[3])) + ((r8[4] + r8[5]) + (r8[6] + r8[7]));
    float other = __shfl_xor(hs, 1);
    if (h == 0) S2a[j] = hs + other;   // fl(hs0 + hs1) — np order
    for (int i = 0; i < 128; i += 8) {
        ushort u8[8];
        #pragma unroll
        for (int l = 0; l < 8; ++l) u8[l] = f2bf(a[i + l]);
        *(ushort4*)(orow + i)     = make_ushort4(u8[0], u8[1], u8[2], u8[3]);
        *(ushort4*)(orow + i + 4) = make_ushort4(u8[4], u8[5], u8[6], u8[7]);
    }
}

// ---------------------------------------------------------------------------
// bf16 MFMA GEMM, global_load_lds staging w/ XOR-swizzled LDS layout.
// Emits per (row, 64-col block) min approx score: bmins[row][cb], cb=by*2+wc.
// score = S2[j] - 2 * x.w  (S1 omitted: constant per row)
// ---------------------------------------------------------------------------
__global__ __launch_bounds__(256) void gemm_min(const ushort* __restrict__ A,
                                                const ushort* __restrict__ Bm,
                                                const float* __restrict__ S2a,
                                                float* __restrict__ bmins) {
    __shared__ __attribute__((aligned(16))) ushort As[8192];  // [128][64], swizzled
    __shared__ __attribute__((aligned(16))) ushort Bs[8192];

    const int n0 = blockIdx.x * 128;
    const int j0 = blockIdx.y * 128;
    const int t  = threadIdx.x;
    const int wv = t >> 6, l = t & 63;
    const int wr = wv >> 1, wc = wv & 1;
    const int q  = l >> 4, c = l & 15;

    // staging lane constants: chunk = 8 rows x (8 x 16B); lane l -> row l>>3,
    // LDS chunk-in-row l&7 which holds global chunk (l&7)^(row&7)
    const int lr = l >> 3;
    const int lperm = (l & 7) ^ lr;
    const size_t gA0 = ((size_t)(n0 + wv * 32 + lr) << 8) + lperm * 8;
    const size_t gB0 = ((size_t)(j0 + wv * 32 + lr) << 8) + lperm * 8;
    const int ldsbase = wv * 4 * 512;   // wave wv stages chunks wv*4..wv*4+3

    floatx4 acc[4][4];
    #pragma unroll
    for (int mi = 0; mi < 4; ++mi)
        #pragma unroll
        for (int ni = 0; ni < 4; ++ni)
            acc[mi][ni] = (floatx4){0.f, 0.f, 0.f, 0.f};

    for (int kb = 0; kb < 4; ++kb) {
        if (kb) __syncthreads();
        #pragma unroll
        for (int ca = 0; ca < 4; ++ca) {
            gl_lds16(A + gA0 + ca * 2048 + kb * 64, As + ldsbase + ca * 512);
            gl_lds16(Bm + gB0 + ca * 2048 + kb * 64, Bs + ldsbase + ca * 512);
        }
        __syncthreads();
        #pragma unroll
        for (int kk = 0; kk < 2; ++kk) {
            short8 af[4], bf[4];
            #pragma unroll
            for (int mi = 0; mi < 4; ++mi) {
                int row = wr * 64 + mi * 16 + c;
                int pos = (kk * 4 + q) ^ (c & 7);
                af[mi] = *(const short8*)&As[row * 64 + pos * 8];
            }
            #pragma unroll
            for (int ni = 0; ni < 4; ++ni) {
                int row = wc * 64 + ni * 16 + c;
                int pos = (kk * 4 + q) ^ (c & 7);
                bf[ni] = *(const short8*)&Bs[row * 64 + pos * 8];
            }
            #pragma unroll
            for (int mi = 0; mi < 4; ++mi)
                #pragma unroll
                for (int ni = 0; ni < 4; ++ni)
                    acc[mi][ni] = __builtin_amdgcn_mfma_f32_16x16x32_bf16(
                        af[mi], bf[ni], acc[mi][ni], 0, 0, 0);
        }
    }

    float cn[4];
    #pragma unroll
    for (int ni = 0; ni < 4; ++ni) cn[ni] = S2a[j0 + wc * 64 + ni * 16 + c];

    #pragma unroll
    for (int mi = 0; mi < 4; ++mi) {
        #pragma unroll
        for (int r = 0; r < 4; ++r) {
            float v0 = fminf(fmaf(-2.f, acc[mi][0][r], cn[0]),
                             fmaf(-2.f, acc[mi][1][r], cn[1]));
            float v1 = fminf(fmaf(-2.f, acc[mi][2][r], cn[2]),
                             fmaf(-2.f, acc[mi][3][r], cn[3]));
            float m = fminf(v0, v1);
            #pragma unroll
            for (int off = 1; off <= 8; off <<= 1)
                m = fminf(m, __shfl_xor(m, off));
            if (c == 0) {
                int row = wr * 64 + mi * 16 + q * 4 + r;
                bmins[((size_t)(n0 + row) << 8) + blockIdx.y * 2 + wc] = m;
            }
        }
    }
}

// ---------------------------------------------------------------------------
// Per row: find min over 256 block-mins, exactly rescore (np-fp32 mirror) all
// codes of blocks within MARGIN; argmin with first-index tie-break.
// Also computes S1 (np pairwise) and zeroes loss (block 0).
// ---------------------------------------------------------------------------
__global__ __launch_bounds__(256) void rescore2(const float* __restrict__ bmins,
                                                const float* __restrict__ xf32,
                                                const float* __restrict__ w,
                                                const float* __restrict__ S2a,
                                                int* __restrict__ idxb,
                                                float* __restrict__ xcode,
                                                float* __restrict__ loss) {
#pragma clang fp contract(off)
    __shared__ float xrow[256];
    __shared__ float red[256];
    __shared__ unsigned long long redk[256];
    __shared__ int list[256];
    __shared__ int np_;
    __shared__ float sS1[2];
    const int n = blockIdx.x, t = threadIdx.x;
    if (n == 0 && t == 0) *loss = 0.f;
    xrow[t] = xf32[((size_t)n << 8) + t];
    const float bm = bmins[((size_t)n << 8) + t];
    red[t] = bm;
    if (t == 0) np_ = 0;
    __syncthreads();
    for (int s = 128; s > 0; s >>= 1) {
        if (t < s) red[t] = fminf(red[t], red[t + s]);
        __syncthreads();
    }
    const float thr = red[0] + MARGIN;
    if (bm <= thr) { int p = atomicAdd(&np_, 1); list[p] = t; }
    if (t < 2) {   // exact np pairwise S1 halves
        const float* a = &xrow[t * 128];
        float r8[8];
        #pragma unroll
        for (int l = 0; l < 8; ++l) { float v = a[l]; r8[l] = v * v; }
        for (int i = 8; i < 128; i += 8) {
            #pragma unroll
            for (int l = 0; l < 8; ++l) { float v = a[i + l]; r8[l] = r8[l] + v * v; }
        }
        sS1[t] = ((r8[0] + r8[1]) + (r8[2] + r8[3])) + ((r8[4] + r8[5]) + (r8[6] + r8[7]));
    }
    __syncthreads();
    const int total = np_ * 64;
    const float S1n = sS1[0] + sS1[1];
    unsigned long long best = ~0ull;
    for (int it = t; it < total; it += 256) {
        const int j = list[it >> 6] * 64 + (it & 63);
        const float* wr_ = w + ((size_t)j << 8);
        float g = 0.f;
        for (int k = 0; k < 256; ++k) g = fmaf(xrow[k], wr_[k], g);  // BLAS k-order
        float d = (S1n + S2a[j]) - 2.0f * g;   // 2g exact; single final rounding
        unsigned long long key = ((unsigned long long)fsort(d) << 32) | (unsigned)j;
        if (key < best) best = key;
    }
    redk[t] = best;
    __syncthreads();
    for (int s = 128; s > 0; s >>= 1) {
        if (t < s) { if (redk[t + s] < redk[t]) redk[t] = redk[t + s]; }
        __syncthreads();
    }
    if (t == 0) {
        int J = (int)(redk[0] & 0xffffffffu);
        idxb[n] = J;
        xcode[n] = (float)J;
    }
}

// ---------------------------------------------------------------------------
// xq_img gather + loss
// ---------------------------------------------------------------------------
__global__ __launch_bounds__(256) void outputs_k(const float* __restrict__ x,
                                                 const float* __restrict__ w,
                                                 const int* __restrict__ idxb,
                                                 float* __restrict__ out,
                                                 float* __restrict__ loss) {
    const int b = blockIdx.x, hq = blockIdx.y, cs = blockIdx.z;
    const int t = threadIdx.x;
    const int hw = hq * 256 + t;
    const int n = (b << 10) + hw;
    const int id = idxb[n];
    float lacc = 0.f;
    for (int ci = 0; ci < 32; ++ci) {
        const int c_ = cs * 32 + ci;
        const size_t oo = ((size_t)((b << 8) + c_) << 10) + hw;
        float wv = w[((size_t)id << 8) + c_];
        float xv = x[oo];
        out[oo] = wv;
        float d = wv - xv;
        lacc = fmaf(d, d, lacc);
    }
    #pragma unroll
    for (int off = 32; off; off >>= 1) lacc += __shfl_xor(lacc, off);
    __shared__ float part[4];
    if ((t & 63) == 0) part[t >> 6] = lacc;
    __syncthreads();
    if (t == 0) {
        float p = part[0] + part[1] + part[2] + part[3];
        atomicAdd(loss, p * (1.25f / 2097152.0f));
    }
}

// ---------------------------------------------------------------------------
extern "C" void kernel_launch(void* const* d_in, const int* in_sizes, int n_in,
                              void* d_out, int out_size, void* d_ws, size_t ws_size,
                              hipStream_t stream) {
    const float* x = (const float*)d_in[0];
    const float* w = (const float*)d_in[1];
    float* out = (float*)d_out;

    char* ws = (char*)d_ws;
    const size_t MB = 1024u * 1024u;
    ushort* xbf   = (ushort*)(ws);                   //  4 MiB
    float*  xf32  = (float*) (ws + 4 * MB);          //  8 MiB
    ushort* wbf   = (ushort*)(ws + 12 * MB);         //  8 MiB
    float*  S2a   = (float*) (ws + 20 * MB);         // 64 KiB
    float*  bmins = (float*) (ws + 21 * MB);         //  8 MiB
    int*    idxb  = (int*)   (ws + 29 * MB);         // 32 KiB

    float* loss_ptr  = out + 2097152;
    float* xcode_ptr = out + 2097153;

    prep_x  <<<dim3(8, 32, 8), 256, 0, stream>>>(x, xf32, xbf);
    prep_w2 <<<dim3(128),      256, 0, stream>>>(w, wbf, S2a);
    gemm_min<<<dim3(64, 128),  256, 0, stream>>>(xbf, wbf, S2a, bmins);
    rescore2<<<dim3(8192),     256, 0, stream>>>(bmins, xf32, w, S2a, idxb,
                                                 xcode_ptr, loss_ptr);
    outputs_k<<<dim3(8, 4, 8), 256, 0, stream>>>(x, w, idxb, out, loss_ptr);
}

// Round 4
// 277.938 us; speedup vs baseline: 1.2537x; 1.1381x over previous
//
#include <hip/hip_runtime.h>
#include <stdint.h>

#define NROW    8192
#define CDIM    256
#define NCODE   16384
#define MARGINF 1.6e-4f

typedef short short8 __attribute__((ext_vector_type(8)));
typedef float floatx4 __attribute__((ext_vector_type(4)));
typedef _Float16 half2v __attribute__((ext_vector_type(2)));

__device__ inline ushort f2bf(float f) {
    unsigned u = __builtin_bit_cast(unsigned, f);
    unsigned r = (u + 0x7fffu + ((u >> 16) & 1u)) >> 16;
    return (ushort)r;
}
__device__ inline unsigned fsort(float v) {
    unsigned u = __builtin_bit_cast(unsigned, v);
    return (u >> 31) ? ~u : (u | 0x80000000u);
}
__device__ inline unsigned pk_min(unsigned a, unsigned b) {
    half2v x = __builtin_bit_cast(half2v, a);
    half2v y = __builtin_bit_cast(half2v, b);
    half2v r;
    r[0] = x[0] < y[0] ? x[0] : y[0];
    r[1] = x[1] < y[1] ? x[1] : y[1];
    return __builtin_bit_cast(unsigned, r);
}

__device__ inline void gl_lds16(const ushort* g, ushort* lds) {
    __builtin_amdgcn_global_load_lds(
        (const __attribute__((address_space(1))) unsigned int*)(g),
        (__attribute__((address_space(3))) unsigned int*)(lds),
        16, 0, 0);
}

// ---------------------------------------------------------------------------
// x (B,C,H,W) fp32 -> xf32[n][c] and xbf[n][c] (bf16), n = b*1024 + hw
// ---------------------------------------------------------------------------
__global__ __launch_bounds__(256) void prep_x(const float* __restrict__ x,
                                              float* __restrict__ xf32,
                                              ushort* __restrict__ xbf) {
    __shared__ float tile[32][33];
    const int b = blockIdx.x, ht = blockIdx.y, ct = blockIdx.z;
    const int t = threadIdx.x;
    const int hw0 = ht * 32, c0 = ct * 32;
    {
        const int cc = t >> 5, hh = t & 31;
        #pragma unroll
        for (int i = 0; i < 4; ++i) {
            int cl = cc + i * 8;
            tile[cl][hh] = x[((size_t)(b * 256 + c0 + cl) << 10) + hw0 + hh];
        }
    }
    __syncthreads();
    {
        const int col = t & 31, row = t >> 5;
        #pragma unroll
        for (int i = 0; i < 4; ++i) {
            int r = row + i * 8;
            float v = tile[col][r];
            size_t o = ((size_t)(b * 1024 + hw0 + r) << 8) + c0 + col;
            xf32[o] = v;
            xbf[o] = f2bf(v);
        }
    }
}

// ---------------------------------------------------------------------------
// 2 threads per code j (one per 128-half): bf16 copy + exact np pairwise S2
// ---------------------------------------------------------------------------
__global__ __launch_bounds__(256) void prep_w2(const float* __restrict__ w,
                                               ushort* __restrict__ wbf,
                                               float* __restrict__ S2a) {
#pragma clang fp contract(off)
    const int gt = blockIdx.x * 256 + threadIdx.x;
    const int j = gt >> 1, h = gt & 1;
    const float* a = w + ((size_t)j << 8) + h * 128;
    ushort* orow = wbf + ((size_t)j << 8) + h * 128;
    float r8[8];
    #pragma unroll
    for (int l = 0; l < 8; ++l) { float v = a[l]; r8[l] = v * v; }
    for (int i = 8; i < 128; i += 8) {
        #pragma unroll
        for (int l = 0; l < 8; ++l) { float v = a[i + l]; r8[l] = r8[l] + v * v; }
    }
    float hs = ((r8[0] + r8[1]) + (r8[2] + r8[3])) + ((r8[4] + r8[5]) + (r8[6] + r8[7]));
    float other = __shfl_xor(hs, 1);
    if (h == 0) S2a[j] = hs + other;   // fl(hs0 + hs1) — np order
    for (int i = 0; i < 128; i += 8) {
        ushort u8[8];
        #pragma unroll
        for (int l = 0; l < 8; ++l) u8[l] = f2bf(a[i + l]);
        *(ushort4*)(orow + i)     = make_ushort4(u8[0], u8[1], u8[2], u8[3]);
        *(ushort4*)(orow + i + 4) = make_ushort4(u8[4], u8[5], u8[6], u8[7]);
    }
}

// ---------------------------------------------------------------------------
// bf16 MFMA GEMM, global_load_lds staging, XOR-swizzled LDS layout.
// Emits per (row, 16-col block) min approx score as fp16, two blocks per u32:
//   bm32[row][512]; u32 index = blockIdx.y*4 + wc*2 + p  (p=0: ni 0,1; p=1: ni 2,3)
// score = S2[j] - 2 * x.w  (S1 omitted: constant per row)
// ---------------------------------------------------------------------------
__global__ __launch_bounds__(256) void gemm_min(const ushort* __restrict__ A,
                                                const ushort* __restrict__ Bm,
                                                const float* __restrict__ S2a,
                                                unsigned* __restrict__ bm32) {
    __shared__ __attribute__((aligned(16))) ushort As[8192];  // [128][64], swizzled
    __shared__ __attribute__((aligned(16))) ushort Bs[8192];

    const int n0 = blockIdx.x * 128;
    const int j0 = blockIdx.y * 128;
    const int t  = threadIdx.x;
    const int wv = t >> 6, l = t & 63;
    const int wr = wv >> 1, wc = wv & 1;
    const int q  = l >> 4, c = l & 15;

    const int lr = l >> 3;
    const int lperm = (l & 7) ^ lr;
    const size_t gA0 = ((size_t)(n0 + wv * 32 + lr) << 8) + lperm * 8;
    const size_t gB0 = ((size_t)(j0 + wv * 32 + lr) << 8) + lperm * 8;
    const int ldsbase = wv * 4 * 512;

    floatx4 acc[4][4];
    #pragma unroll
    for (int mi = 0; mi < 4; ++mi)
        #pragma unroll
        for (int ni = 0; ni < 4; ++ni)
            acc[mi][ni] = (floatx4){0.f, 0.f, 0.f, 0.f};

    for (int kb = 0; kb < 4; ++kb) {
        if (kb) __syncthreads();
        #pragma unroll
        for (int ca = 0; ca < 4; ++ca) {
            gl_lds16(A + gA0 + ca * 2048 + kb * 64, As + ldsbase + ca * 512);
            gl_lds16(Bm + gB0 + ca * 2048 + kb * 64, Bs + ldsbase + ca * 512);
        }
        __syncthreads();
        #pragma unroll
        for (int kk = 0; kk < 2; ++kk) {
            short8 af[4], bf[4];
            #pragma unroll
            for (int mi = 0; mi < 4; ++mi) {
                int row = wr * 64 + mi * 16 + c;
                int pos = (kk * 4 + q) ^ (c & 7);
                af[mi] = *(const short8*)&As[row * 64 + pos * 8];
            }
            #pragma unroll
            for (int ni = 0; ni < 4; ++ni) {
                int row = wc * 64 + ni * 16 + c;
                int pos = (kk * 4 + q) ^ (c & 7);
                bf[ni] = *(const short8*)&Bs[row * 64 + pos * 8];
            }
            #pragma unroll
            for (int mi = 0; mi < 4; ++mi)
                #pragma unroll
                for (int ni = 0; ni < 4; ++ni)
                    acc[mi][ni] = __builtin_amdgcn_mfma_f32_16x16x32_bf16(
                        af[mi], bf[ni], acc[mi][ni], 0, 0, 0);
        }
    }

    float cn[4];
    #pragma unroll
    for (int ni = 0; ni < 4; ++ni) cn[ni] = S2a[j0 + wc * 64 + ni * 16 + c];

    #pragma unroll
    for (int mi = 0; mi < 4; ++mi) {
        #pragma unroll
        for (int r = 0; r < 4; ++r) {
            float v0 = fmaf(-2.f, acc[mi][0][r], cn[0]);
            float v1 = fmaf(-2.f, acc[mi][1][r], cn[1]);
            float v2 = fmaf(-2.f, acc[mi][2][r], cn[2]);
            float v3 = fmaf(-2.f, acc[mi][3][r], cn[3]);
            half2v p0, p1;
            p0[0] = (_Float16)v0; p0[1] = (_Float16)v1;
            p1[0] = (_Float16)v2; p1[1] = (_Float16)v3;
            unsigned u0 = __builtin_bit_cast(unsigned, p0);
            unsigned u1 = __builtin_bit_cast(unsigned, p1);
            #pragma unroll
            for (int off = 1; off <= 8; off <<= 1) {
                u0 = pk_min(u0, (unsigned)__shfl_xor((int)u0, off));
                u1 = pk_min(u1, (unsigned)__shfl_xor((int)u1, off));
            }
            if (c == 0) {
                int row = wr * 64 + mi * 16 + q * 4 + r;
                size_t base = ((size_t)(n0 + row) << 9) + blockIdx.y * 4 + wc * 2;
                bm32[base]     = u0;
                bm32[base + 1] = u1;
            }
        }
    }
}

// ---------------------------------------------------------------------------
// Per row: min over 1024 16-block mins (fp16-packed), exactly rescore
// (np-fp32 mirror) all codes of 16-blocks within MARGIN; first-index ties.
// Also computes S1 (np pairwise) and zeroes loss (block 0).
// ---------------------------------------------------------------------------
__global__ __launch_bounds__(256) void rescore2(const unsigned* __restrict__ bm32,
                                                const float* __restrict__ xf32,
                                                const float* __restrict__ w,
                                                const float* __restrict__ S2a,
                                                int* __restrict__ idxb,
                                                float* __restrict__ xcode,
                                                float* __restrict__ loss) {
#pragma clang fp contract(off)
    __shared__ float xrow[256];
    __shared__ float red[256];
    __shared__ unsigned long long redk[256];
    __shared__ short list[1024];
    __shared__ int np_;
    __shared__ float sS1[2];
    const int n = blockIdx.x, t = threadIdx.x;
    if (n == 0 && t == 0) *loss = 0.f;
    if (t == 0) np_ = 0;
    xrow[t] = xf32[((size_t)n << 8) + t];
    const uint2 bm = *(const uint2*)(bm32 + ((size_t)n << 9) + t * 2);
    const half2v ha = __builtin_bit_cast(half2v, bm.x);
    const half2v hb = __builtin_bit_cast(half2v, bm.y);
    float v4[4] = {(float)ha[0], (float)ha[1], (float)hb[0], (float)hb[1]};
    float m = fminf(fminf(v4[0], v4[1]), fminf(v4[2], v4[3]));
    red[t] = m;
    __syncthreads();
    for (int s = 128; s > 0; s >>= 1) {
        if (t < s) red[t] = fminf(red[t], red[t + s]);
        __syncthreads();
    }
    const float thr = red[0] + MARGINF;
    #pragma unroll
    for (int i = 0; i < 4; ++i)
        if (v4[i] <= thr) { int p = atomicAdd(&np_, 1); list[p] = (short)(t * 4 + i); }
    if (t < 2) {   // exact np pairwise S1 halves
        const float* a = &xrow[t * 128];
        float r8[8];
        #pragma unroll
        for (int l = 0; l < 8; ++l) { float v = a[l]; r8[l] = v * v; }
        for (int i = 8; i < 128; i += 8) {
            #pragma unroll
            for (int l = 0; l < 8; ++l) { float v = a[i + l]; r8[l] = r8[l] + v * v; }
        }
        sS1[t] = ((r8[0] + r8[1]) + (r8[2] + r8[3])) + ((r8[4] + r8[5]) + (r8[6] + r8[7]));
    }
    __syncthreads();
    const int total = np_ * 16;
    const float S1n = sS1[0] + sS1[1];
    unsigned long long best = ~0ull;
    for (int it = t; it < total; it += 256) {
        const int j = (int)list[it >> 4] * 16 + (it & 15);
        const float* wr_ = w + ((size_t)j << 8);
        float g = 0.f;
        for (int k = 0; k < 256; k += 4) {   // sequential FMA in k-order (BLAS)
            float4 wv = *(const float4*)(wr_ + k);
            g = fmaf(xrow[k],     wv.x, g);
            g = fmaf(xrow[k + 1], wv.y, g);
            g = fmaf(xrow[k + 2], wv.z, g);
            g = fmaf(xrow[k + 3], wv.w, g);
        }
        float d = (S1n + S2a[j]) - 2.0f * g;
        unsigned long long key = ((unsigned long long)fsort(d) << 32) | (unsigned)j;
        if (key < best) best = key;
    }
    redk[t] = best;
    __syncthreads();
    for (int s = 128; s > 0; s >>= 1) {
        if (t < s) { if (redk[t + s] < redk[t]) redk[t] = redk[t + s]; }
        __syncthreads();
    }
    if (t == 0) {
        int J = (int)(redk[0] & 0xffffffffu);
        idxb[n] = J;
        xcode[n] = (float)J;
    }
}

// ---------------------------------------------------------------------------
// xq_img gather + loss
// ---------------------------------------------------------------------------
__global__ __launch_bounds__(256) void outputs_k(const float* __restrict__ x,
                                                 const float* __restrict__ w,
                                                 const int* __restrict__ idxb,
                                                 float* __restrict__ out,
                                                 float* __restrict__ loss) {
    const int b = blockIdx.x, hq = blockIdx.y, cs = blockIdx.z;
    const int t = threadIdx.x;
    const int hw = hq * 256 + t;
    const int n = (b << 10) + hw;
    const int id = idxb[n];
    float lacc = 0.f;
    for (int ci = 0; ci < 32; ++ci) {
        const int c_ = cs * 32 + ci;
        const size_t oo = ((size_t)((b << 8) + c_) << 10) + hw;
        float wv = w[((size_t)id << 8) + c_];
        float xv = x[oo];
        out[oo] = wv;
        float d = wv - xv;
        lacc = fmaf(d, d, lacc);
    }
    #pragma unroll
    for (int off = 32; off; off >>= 1) lacc += __shfl_xor(lacc, off);
    __shared__ float part[4];
    if ((t & 63) == 0) part[t >> 6] = lacc;
    __syncthreads();
    if (t == 0) {
        float p = part[0] + part[1] + part[2] + part[3];
        atomicAdd(loss, p * (1.25f / 2097152.0f));
    }
}

// ---------------------------------------------------------------------------
extern "C" void kernel_launch(void* const* d_in, const int* in_sizes, int n_in,
                              void* d_out, int out_size, void* d_ws, size_t ws_size,
                              hipStream_t stream) {
    const float* x = (const float*)d_in[0];
    const float* w = (const float*)d_in[1];
    float* out = (float*)d_out;

    char* ws = (char*)d_ws;
    const size_t MB = 1024u * 1024u;
    ushort*   xbf   = (ushort*)  (ws);                   //  4 MiB
    float*    xf32  = (float*)   (ws + 4 * MB);          //  8 MiB
    ushort*   wbf   = (ushort*)  (ws + 12 * MB);         //  8 MiB
    float*    S2a   = (float*)   (ws + 20 * MB);         // 64 KiB
    unsigned* bm32  = (unsigned*)(ws + 21 * MB);         // 16 MiB
    int*      idxb  = (int*)     (ws + 37 * MB);         // 32 KiB

    float* loss_ptr  = out + 2097152;
    float* xcode_ptr = out + 2097153;

    prep_x  <<<dim3(8, 32, 8), 256, 0, stream>>>(x, xf32, xbf);
    prep_w2 <<<dim3(128),      256, 0, stream>>>(w, wbf, S2a);
    gemm_min<<<dim3(64, 128),  256, 0, stream>>>(xbf, wbf, S2a, bm32);
    rescore2<<<dim3(8192),     256, 0, stream>>>(bm32, xf32, w, S2a, idxb,
                                                 xcode_ptr, loss_ptr);
    outputs_k<<<dim3(8, 4, 8), 256, 0, stream>>>(x, w, idxb, out, loss_ptr);
}